// Round 3
// baseline (1132.622 us; speedup 1.0000x reference)
//
#include <hip/hip_runtime.h>

#define N_NODES 10000
#define N_EDGES 50000
#define IN0     32
#define EDGE_IN 16
#define GIN     8
#define HID     64
#define NG      64
#define KDIM    128
#define KSEG    4
#define EPS     1e-5f

typedef _Float16 f16;
typedef _Float16 v8h __attribute__((ext_vector_type(8)));
typedef float    v4f __attribute__((ext_vector_type(4)));

// ---------------------------------------------------------------------------
// ht[j][e] = f16(relu(ea[e]@w1[:,j] + b1[j]))  -- transposed for the fused GEMM
__global__ __launch_bounds__(256) void ht_kernel(const float* __restrict__ ea,
                                                 const float* __restrict__ w1,
                                                 const float* __restrict__ b1,
                                                 f16* __restrict__ ht) {
    __shared__ float eas[256][17];
    const int e0 = blockIdx.x * 256, t = threadIdx.x;
    for (int idx = t; idx < 256 * 16; idx += 256) {
        int r = idx >> 4, i = idx & 15;
        eas[r][i] = (e0 + r < N_EDGES) ? ea[(size_t)(e0 + r) * EDGE_IN + i] : 0.f;
    }
    __syncthreads();
    const int e = e0 + t;
#pragma unroll 1
    for (int j = 0; j < KDIM; j++) {
        float acc = b1[j];
#pragma unroll
        for (int i = 0; i < EDGE_IN; i++) acc += eas[t][i] * w1[i * KDIM + j];
        if (e < N_EDGES) ht[(size_t)j * N_EDGES + e] = (f16)fmaxf(acc, 0.f);
    }
}

// ---------------------------------------------------------------------------
// xf[idx] = f16(x[idx])
__global__ __launch_bounds__(256) void xconv(const float* __restrict__ x,
                                             f16* __restrict__ xf, int n) {
    int idx = blockIdx.x * 256 + threadIdx.x;
    if (idx < n) xf[idx] = (f16)x[idx];
}

// ---------------------------------------------------------------------------
// Bg[chunk][o][cc] = f16 of B[C=chunk*64+cc, o] where B[k*in+i, o]=w2[k][i*64+o],
// B[in*128+i, o]=b2[i*64+o], else 0.  (chunk = 64 K-rows of the flattened GEMM)
__global__ __launch_bounds__(256) void bconv(const float* __restrict__ w2,
                                             const float* __restrict__ b2,
                                             f16* __restrict__ Bg,
                                             int in, int inshift) {
    const int chunk = blockIdx.x;
    const int inK = in << 7;
    const size_t base = (size_t)chunk * 4096;
    for (int l = threadIdx.x; l < 4096; l += 256) {
        int o = l >> 6, cc = l & 63;
        int C = (chunk << 6) + cc;
        float v = 0.f;
        if (C < inK) {
            int k = C >> inshift, i = C & (in - 1);
            v = w2[(size_t)k * (in << 6) + (i << 6) + o];
        } else if (C < inK + in) {
            v = b2[((C - inK) << 6) + o];
        }
        Bg[base + l] = (f16)v;
    }
}

// ---------------------------------------------------------------------------
// Fused NNConv message+scatter:  agg[dst[e],o] += sum_C (h[e,k]*x[src,i]) * B[C,o]
// Barrier-free version: NO LDS, NO __syncthreads in the K loop. Each wave owns
// 64 edges and reads its B fragments directly from Bg (L2-resident, <=1 MB).
// K additionally split across gridDim.y (KSEG) segments accumulating via the
// same atomicAdd scatter the dst write already requires.
__global__ __launch_bounds__(256) void fused_msg(const f16* __restrict__ ht,
                                                 const f16* __restrict__ xf,
                                                 const f16* __restrict__ Bg,
                                                 const int* __restrict__ src,
                                                 const int* __restrict__ dst,
                                                 float* __restrict__ agg,
                                                 int in, int inshift, int nch) {
    const int t = threadIdx.x;
    const int w = t >> 6, lane = t & 63;
    const int m = lane & 15, q = lane >> 4;
    const int e0 = blockIdx.x * 256;
    const int inK = in << 7;

    // K-segment this block owns (chunk-aligned by construction)
    const int cbeg = (int)(((long)nch * blockIdx.y) / gridDim.y);
    const int cend = (int)(((long)nch * (blockIdx.y + 1)) / gridDim.y);

    // per-lane x fragments: x[v_s][p*32 + q*8 .. +7], fixed for whole K loop
    v8h xr[4][2];
    int eidx[4];
#pragma unroll
    for (int s = 0; s < 4; s++) {
        int e = e0 + w * 64 + s * 16 + m;
        eidx[s] = e < N_EDGES ? e : N_EDGES - 1;
        const f16* xrow = xf + (size_t)src[eidx[s]] * in;
        xr[s][0] = *(const v8h*)(xrow + q * 8);
        if (in == 64) xr[s][1] = *(const v8h*)(xrow + 32 + q * 8);
        else          xr[s][1] = xr[s][0];
    }

    // per-lane base into a B chunk: row o = (tt*16 + m), col = p*32 + q*8
    const f16* bbase = Bg + m * 64 + q * 8;

    v4f acc[4][4] = {};
#pragma unroll 2
    for (int c = cbeg; c < cend; c++) {
        const f16* bc = bbase + (size_t)c * 4096;
#pragma unroll
        for (int p = 0; p < 2; p++) {
            const int c0 = (c << 6) + (p << 5);
            if (c0 < inK + in) {
                const int xs = p & (in >> 6);   // 64->p, 32->0
                f16 hv[4];
                if (c0 < inK) {
                    const int k = c0 >> inshift;
                    const f16* hp = ht + (size_t)k * N_EDGES;
#pragma unroll
                    for (int s = 0; s < 4; s++) hv[s] = hp[eidx[s]];
                } else {
#pragma unroll
                    for (int s = 0; s < 4; s++) hv[s] = (f16)1.0f;
                }
                v8h bf[4];
#pragma unroll
                for (int tt = 0; tt < 4; tt++)
                    bf[tt] = *(const v8h*)(bc + tt * 1024 + p * 32);
#pragma unroll
                for (int s = 0; s < 4; s++) {
                    v8h af;
#pragma unroll
                    for (int j = 0; j < 8; j++) af[j] = xr[s][xs][j] * hv[s];
#pragma unroll
                    for (int tt = 0; tt < 4; tt++)
                        acc[s][tt] = __builtin_amdgcn_mfma_f32_16x16x32_f16(
                            af, bf[tt], acc[s][tt], 0, 0, 0);
                }
            }
        }
    }

    // epilogue: C/D layout col=lane&15, row=quad*4+reg
#pragma unroll
    for (int s = 0; s < 4; s++) {
#pragma unroll
        for (int r = 0; r < 4; r++) {
            const int e = e0 + w * 64 + s * 16 + q * 4 + r;
            if (e < N_EDGES) {
                const int d = dst[e];
#pragma unroll
                for (int tt = 0; tt < 4; tt++)
                    atomicAdd(&agg[(size_t)d * 64 + tt * 16 + m], acc[s][tt][r]);
            }
        }
    }
}

// ---------------------------------------------------------------------------
// pre[n,o] = agg[n,o] + sum_i x[n,i]*root[i,o] + bias[o]; accumulate BN stats.
__global__ __launch_bounds__(256) void pre_stats(const float* __restrict__ agg,
                                                 const float* __restrict__ x,
                                                 const float* __restrict__ root,
                                                 const float* __restrict__ bias,
                                                 float* __restrict__ pre,
                                                 float* __restrict__ stats,
                                                 int in, int inshift) {
    __shared__ float xs[4][64];
    __shared__ float lsum[64], lsq[64];
    const int o = threadIdx.x & 63, nl = threadIdx.x >> 6;
    if (threadIdx.x < 64) { lsum[threadIdx.x] = 0.f; lsq[threadIdx.x] = 0.f; }
    const float bo = bias[o];
    for (int n0 = blockIdx.x * 4; n0 < N_NODES; n0 += gridDim.x * 4) {
        __syncthreads();
        for (int idx = threadIdx.x; idx < (4 << inshift); idx += 256) {
            int r = idx >> inshift, i = idx & (in - 1);
            if (n0 + r < N_NODES) xs[r][i] = x[(size_t)(n0 + r) * in + i];
        }
        __syncthreads();
        int n = n0 + nl;
        if (n < N_NODES) {
            float acc = agg[(size_t)n * 64 + o] + bo;
#pragma unroll 8
            for (int i = 0; i < in; i++) acc += xs[nl][i] * root[i * 64 + o];
            pre[(size_t)n * 64 + o] = acc;
            atomicAdd(&lsum[o], acc);
            atomicAdd(&lsq[o], acc * acc);
        }
    }
    __syncthreads();
    if (threadIdx.x < 64) {
        atomicAdd(&stats[threadIdx.x], lsum[threadIdx.x]);
        atomicAdd(&stats[64 + threadIdx.x], lsq[threadIdx.x]);
    }
}

// ---------------------------------------------------------------------------
// BN (batch stats, biased var) + ReLU. mode 0: store xn. mode 1: segment-max pool.
__global__ __launch_bounds__(256) void bn_apply(const float* __restrict__ pre,
                                                const float* __restrict__ stats,
                                                const float* __restrict__ gamma,
                                                const float* __restrict__ beta,
                                                float* __restrict__ xn,
                                                const int* __restrict__ batch,
                                                float* __restrict__ pooled,
                                                int mode) {
    int idx = blockIdx.x * 256 + threadIdx.x;
    if (idx >= N_NODES * 64) return;
    const int o = idx & 63, n = idx >> 6;
    const float inv = 1.f / (float)N_NODES;
    float mu = stats[o] * inv;
    float var = stats[64 + o] * inv - mu * mu;
    float sc = gamma[o] * rsqrtf(var + EPS);
    float sh = beta[o] - mu * sc;
    float v = fmaxf(pre[idx] * sc + sh, 0.f);
    if (mode == 0) xn[idx] = v;
    else atomicMax((int*)&pooled[(size_t)batch[n] * 64 + o], __float_as_int(v));
}

// ---------------------------------------------------------------------------
// out[g] = pp_b2 + relu(cat(pooled[g],u[g]) @ pp_w1 + pp_b1) @ pp_w2
__global__ __launch_bounds__(64) void final_mlp(const float* __restrict__ pooled,
                                                const float* __restrict__ u,
                                                const float* __restrict__ w1,
                                                const float* __restrict__ b1,
                                                const float* __restrict__ w2,
                                                const float* __restrict__ b2,
                                                float* __restrict__ out) {
    const int g = blockIdx.x, t = threadIdx.x;
    float acc = b1[t];
#pragma unroll 8
    for (int i = 0; i < 64; i++) acc += pooled[g * 64 + i] * w1[i * 64 + t];
#pragma unroll
    for (int j = 0; j < GIN; j++) acc += u[g * GIN + j] * w1[(64 + j) * 64 + t];
    float hv = fmaxf(acc, 0.f) * w2[t];
#pragma unroll
    for (int off = 32; off > 0; off >>= 1) hv += __shfl_down(hv, off, 64);
    if (t == 0) out[g] = hv + b2[0];
}

// ---------------------------------------------------------------------------
extern "C" void kernel_launch(void* const* d_in, const int* in_sizes, int n_in,
                              void* d_out, int out_size, void* d_ws, size_t ws_size,
                              hipStream_t stream) {
    const float* x0      = (const float*)d_in[0];
    const int*   ei      = (const int*)d_in[1];
    const int*   src     = ei;
    const int*   dst     = ei + N_EDGES;
    const float* ea      = (const float*)d_in[2];
    const int*   batch   = (const int*)d_in[3];
    const float* u       = (const float*)d_in[4];
    const float* e0w1    = (const float*)d_in[5];
    const float* e0b1    = (const float*)d_in[6];
    const float* e0w2    = (const float*)d_in[7];
    const float* e0b2    = (const float*)d_in[8];
    const float* root0   = (const float*)d_in[9];
    const float* bias0   = (const float*)d_in[10];
    const float* gamma0  = (const float*)d_in[11];
    const float* beta0   = (const float*)d_in[12];
    const float* ew1     = (const float*)d_in[13];
    const float* eb1     = (const float*)d_in[14];
    const float* ew2     = (const float*)d_in[15];
    const float* eb2     = (const float*)d_in[16];
    const float* rootl   = (const float*)d_in[17];
    const float* biasl   = (const float*)d_in[18];
    const float* gammal  = (const float*)d_in[19];
    const float* betal   = (const float*)d_in[20];
    const float* pp_w1   = (const float*)d_in[21];
    const float* pp_b1   = (const float*)d_in[22];
    const float* pp_w2   = (const float*)d_in[23];
    const float* pp_b2   = (const float*)d_in[24];

    float* ws = (float*)d_ws;
    size_t off = 0;
    f16*   ht     = (f16*)(ws + off); off += (size_t)N_EDGES * KDIM / 2;  // 3.2M fl
    f16*   xf     = (f16*)(ws + off); off += (size_t)N_NODES * 64 / 2;
    f16*   Bg     = (f16*)(ws + off); off += (size_t)129 * 4096 / 2;
    float* agg    = ws + off; off += (size_t)N_NODES * 64;
    float* xa     = ws + off; off += (size_t)N_NODES * 64;
    float* xb     = ws + off; off += (size_t)N_NODES * 64;
    float* stats  = ws + off; off += 256;
    float* pooled = ws + off; off += (size_t)NG * 64;

    hipMemsetAsync(pooled, 0, (size_t)NG * 64 * 4, stream);

    struct Layer {
        const float *w1, *b1, *w2, *b2, *root, *bias, *gamma, *beta, *xin;
        float* xout; int in, inshift, mode;
    };
    Layer L[4];
    L[0] = {e0w1, e0b1, e0w2, e0b2, root0, bias0, gamma0, beta0, x0, xa, IN0, 5, 0};
    for (int l = 0; l < 3; l++) {
        const float* xin  = (l == 0) ? xa : ((l == 1) ? xb : xa);
        float*       xout = (l == 0) ? xb : ((l == 1) ? xa : nullptr);
        L[l + 1] = {ew1 + (size_t)l * EDGE_IN * KDIM, eb1 + (size_t)l * KDIM,
                    ew2 + (size_t)l * KDIM * (HID * HID), eb2 + (size_t)l * (HID * HID),
                    rootl + (size_t)l * HID * HID, biasl + (size_t)l * HID,
                    gammal + (size_t)l * HID, betal + (size_t)l * HID,
                    xin, xout, HID, 6, (l == 2) ? 1 : 0};
    }

    const int eblocks = (N_EDGES + 255) / 256;               // 196
    const int ablocks = (N_NODES * 64 + 255) / 256;

    for (int l = 0; l < 4; l++) {
        const Layer& P = L[l];
        // nch: ceil((in*128 + in) / 64)
        const int nch = (P.in * 129 + 63) / 64;
        ht_kernel<<<eblocks, 256, 0, stream>>>(ea, P.w1, P.b1, ht);
        xconv<<<(N_NODES * P.in + 255) / 256, 256, 0, stream>>>(P.xin, xf, N_NODES * P.in);
        bconv<<<nch, 256, 0, stream>>>(P.w2, P.b2, Bg, P.in, P.inshift);
        hipMemsetAsync(agg, 0, (size_t)N_NODES * 64 * 4, stream);
        hipMemsetAsync(stats, 0, 128 * 4, stream);
        fused_msg<<<dim3(eblocks, KSEG), 256, 0, stream>>>(ht, xf, Bg, src, dst, agg,
                                                           P.in, P.inshift, nch);
        pre_stats<<<512, 256, 0, stream>>>(agg, P.xin, P.root, P.bias, agg, stats,
                                           P.in, P.inshift);
        bn_apply<<<ablocks, 256, 0, stream>>>(agg, stats, P.gamma, P.beta, P.xout,
                                              batch, pooled, P.mode);
    }
    final_mlp<<<NG, 64, 0, stream>>>(pooled, u, pp_w1, pp_b1, pp_w2, pp_b2,
                                     (float*)d_out);
}

// Round 4
// 858.469 us; speedup vs baseline: 1.3194x; 1.3194x over previous
//
#include <hip/hip_runtime.h>

#define N_NODES 10000
#define N_EDGES 50000
#define IN0     32
#define EDGE_IN 16
#define GIN     8
#define HID     64
#define NG      64
#define KDIM    128
#define KSEG    4
#define EPS     1e-5f

typedef _Float16 f16;
typedef _Float16 v8h __attribute__((ext_vector_type(8)));
typedef float    v4f __attribute__((ext_vector_type(4)));

// ---------------------------------------------------------------------------
// ht[j][e] = f16(relu(ea[e]@w1[:,j] + b1[j]))  -- transposed for the fused GEMM
__global__ __launch_bounds__(256) void ht_kernel(const float* __restrict__ ea,
                                                 const float* __restrict__ w1,
                                                 const float* __restrict__ b1,
                                                 f16* __restrict__ ht) {
    __shared__ float eas[256][17];
    const int e0 = blockIdx.x * 256, t = threadIdx.x;
    for (int idx = t; idx < 256 * 16; idx += 256) {
        int r = idx >> 4, i = idx & 15;
        eas[r][i] = (e0 + r < N_EDGES) ? ea[(size_t)(e0 + r) * EDGE_IN + i] : 0.f;
    }
    __syncthreads();
    const int e = e0 + t;
#pragma unroll 1
    for (int j = 0; j < KDIM; j++) {
        float acc = b1[j];
#pragma unroll
        for (int i = 0; i < EDGE_IN; i++) acc += eas[t][i] * w1[i * KDIM + j];
        if (e < N_EDGES) ht[(size_t)j * N_EDGES + e] = (f16)fmaxf(acc, 0.f);
    }
}

// ---------------------------------------------------------------------------
// xf[idx] = f16(x[idx])
__global__ __launch_bounds__(256) void xconv(const float* __restrict__ x,
                                             f16* __restrict__ xf, int n) {
    int idx = blockIdx.x * 256 + threadIdx.x;
    if (idx < n) xf[idx] = (f16)x[idx];
}

// ---------------------------------------------------------------------------
// Bg[chunk][o][cc] = f16 of B[C=chunk*64+cc, o] where B[k*in+i, o]=w2[k][i*64+o],
// B[in*128+i, o]=b2[i*64+o], else 0.  (chunk = 64 K-rows of the flattened GEMM)
__global__ __launch_bounds__(256) void bconv(const float* __restrict__ w2,
                                             const float* __restrict__ b2,
                                             f16* __restrict__ Bg,
                                             int in, int inshift) {
    const int chunk = blockIdx.x;
    const int inK = in << 7;
    const size_t base = (size_t)chunk * 4096;
    for (int l = threadIdx.x; l < 4096; l += 256) {
        int o = l >> 6, cc = l & 63;
        int C = (chunk << 6) + cc;
        float v = 0.f;
        if (C < inK) {
            int k = C >> inshift, i = C & (in - 1);
            v = w2[(size_t)k * (in << 6) + (i << 6) + o];
        } else if (C < inK + in) {
            v = b2[((C - inK) << 6) + o];
        }
        Bg[base + l] = (f16)v;
    }
}

// ---------------------------------------------------------------------------
// Fused NNConv message+scatter:  agg[dst[e],o] += sum_C (h[e,k]*x[src,i]) * B[C,o]
// M=256 edges/block (4 waves x 64), N=64, K streamed in 64-chunks via LDS dbuf.
// K split across gridDim.y (KSEG) segments accumulating via atomics.
// NEW: the segment's ht slice (h[e, k] for this block's 256 edges, all pure-k
// rows of the segment = exactly 32 rows x 256 edges x 2B = 16 KB) is staged
// into LDS ONCE with bulk coalesced uint4 loads. The K loop then has NO
// HBM-latency loads on its critical path (ht is 12.8 MB, never L2-resident;
// per-chunk hv gathers were ~900cy round trips serialized by the barrier).
__global__ __launch_bounds__(256) void fused_msg(const f16* __restrict__ ht,
                                                 const f16* __restrict__ xf,
                                                 const f16* __restrict__ Bg,
                                                 const int* __restrict__ src,
                                                 const int* __restrict__ dst,
                                                 float* __restrict__ agg,
                                                 int in, int inshift, int nch) {
    __shared__ f16 Bs[2][64 * 72];   // rows padded 64->72 f16 to break bank stride
    __shared__ f16 hts[32 * 256];    // [krel][e_local] staged ht slice (16 KB)
    __shared__ int dst_l[256];
    const int t = threadIdx.x;
    const int w = t >> 6, lane = t & 63;
    const int m = lane & 15, q = lane >> 4;
    const int e0 = blockIdx.x * 256;
    const int inK = in << 7;

    // K-segment this block owns (chunk-aligned by construction)
    const int cbeg = (int)(((long)nch * blockIdx.y) / gridDim.y);
    const int cend = (int)(((long)nch * (blockIdx.y + 1)) / gridDim.y);
    const int cpure = in << 1;                    // chunks below this are pure-k
    const int cpe = (cend < cpure) ? cend : cpure;
    const int kps = 6 - inshift;                  // log2(k-rows per chunk)
    const int kb0 = cbeg << kps;                  // first staged k row
    const int nrows = (cpe - cbeg) << kps;        // == 32 for all layers/segments

    dst_l[t] = (e0 + t < N_EDGES) ? dst[e0 + t] : -1;

    // bulk-stage ht rows [kb0, kb0+nrows) x edges [e0, e0+256) -> hts
    // (tail-block overrun reads stay inside the workspace; garbage only feeds
    //  edges >= N_EDGES which the epilogue discards)
    for (int i = t; i < (nrows << 5); i += 256) {
        const int row = i >> 5, sg = i & 31;
        const uint4* gp = (const uint4*)(ht + (size_t)(kb0 + row) * N_EDGES + e0 + (sg << 3));
        ((uint4*)hts)[(row << 5) + sg] = *gp;
    }

    // per-lane x fragments: x[v_s][p*32 + q*8 .. +7], fixed for whole K loop
    v8h xr[4][2];
    int eidx[4];
#pragma unroll
    for (int s = 0; s < 4; s++) {
        int e = e0 + w * 64 + s * 16 + m;
        eidx[s] = e < N_EDGES ? e : N_EDGES - 1;
        const f16* xrow = xf + (size_t)src[eidx[s]] * in;
        xr[s][0] = *(const v8h*)(xrow + q * 8);
        if (in == 64) xr[s][1] = *(const v8h*)(xrow + 32 + q * 8);
        else          xr[s][1] = xr[s][0];
    }

    // B staging geometry: thread copies 16 f16 (32B): row so, segment sseg
    const int so = t >> 2, sseg = t & 3;
    const size_t goff = (size_t)so * 64 + sseg * 16;
    const int    loff = so * 72 + sseg * 16;
    {
        const uint4* gp = (const uint4*)(Bg + (size_t)cbeg * 4096 + goff);
        *((uint4*)(&Bs[0][loff]))     = gp[0];
        *((uint4*)(&Bs[0][loff + 8])) = gp[1];
    }
    __syncthreads();

    v4f acc[4][4] = {};
    int buf = 0;
    for (int c = cbeg; c < cend; c++) {
        uint4 r0, r1;
        const bool pf = (c + 1 < cend);
        if (pf) {
            const uint4* gp = (const uint4*)(Bg + (size_t)(c + 1) * 4096 + goff);
            r0 = gp[0]; r1 = gp[1];
        }
        const f16* bb = Bs[buf];
#pragma unroll
        for (int p = 0; p < 2; p++) {
            const int c0 = (c << 6) + (p << 5);
            if (c0 < inK + in) {
                const int xs = p & (in >> 6);   // 64->p, 32->0
                f16 hv[4];
                if (c < cpe) {                  // pure chunk: hv from LDS
                    const int krow = (c0 >> inshift) - kb0;
                    const f16* hp = hts + (krow << 8) + (w << 6);
#pragma unroll
                    for (int s = 0; s < 4; s++) hv[s] = hp[(s << 4) + m];
                } else {                        // bias tail: hv = 1
#pragma unroll
                    for (int s = 0; s < 4; s++) hv[s] = (f16)1.0f;
                }
                v8h bf[4];
#pragma unroll
                for (int tt = 0; tt < 4; tt++)
                    bf[tt] = *(const v8h*)(bb + (tt * 16 + m) * 72 + p * 32 + q * 8);
#pragma unroll
                for (int s = 0; s < 4; s++) {
                    v8h af;
#pragma unroll
                    for (int j = 0; j < 8; j++) af[j] = xr[s][xs][j] * hv[s];
#pragma unroll
                    for (int tt = 0; tt < 4; tt++)
                        acc[s][tt] = __builtin_amdgcn_mfma_f32_16x16x32_f16(
                            af, bf[tt], acc[s][tt], 0, 0, 0);
                }
            }
        }
        if (pf) {
            *((uint4*)(&Bs[buf ^ 1][loff]))     = r0;
            *((uint4*)(&Bs[buf ^ 1][loff + 8])) = r1;
        }
        __syncthreads();
        buf ^= 1;
    }

    // epilogue: C/D layout col=lane&15, row=quad*4+reg
#pragma unroll
    for (int s = 0; s < 4; s++) {
        const int el = w * 64 + s * 16 + q * 4;
#pragma unroll
        for (int r = 0; r < 4; r++) {
            const int d = dst_l[el + r];
            if (d >= 0) {
#pragma unroll
                for (int tt = 0; tt < 4; tt++)
                    atomicAdd(&agg[(size_t)d * 64 + tt * 16 + m], acc[s][tt][r]);
            }
        }
    }
}

// ---------------------------------------------------------------------------
// pre[n,o] = agg[n,o] + sum_i x[n,i]*root[i,o] + bias[o]; accumulate BN stats.
__global__ __launch_bounds__(256) void pre_stats(const float* __restrict__ agg,
                                                 const float* __restrict__ x,
                                                 const float* __restrict__ root,
                                                 const float* __restrict__ bias,
                                                 float* __restrict__ pre,
                                                 float* __restrict__ stats,
                                                 int in, int inshift) {
    __shared__ float xs[4][64];
    __shared__ float lsum[64], lsq[64];
    const int o = threadIdx.x & 63, nl = threadIdx.x >> 6;
    if (threadIdx.x < 64) { lsum[threadIdx.x] = 0.f; lsq[threadIdx.x] = 0.f; }
    const float bo = bias[o];
    for (int n0 = blockIdx.x * 4; n0 < N_NODES; n0 += gridDim.x * 4) {
        __syncthreads();
        for (int idx = threadIdx.x; idx < (4 << inshift); idx += 256) {
            int r = idx >> inshift, i = idx & (in - 1);
            if (n0 + r < N_NODES) xs[r][i] = x[(size_t)(n0 + r) * in + i];
        }
        __syncthreads();
        int n = n0 + nl;
        if (n < N_NODES) {
            float acc = agg[(size_t)n * 64 + o] + bo;
#pragma unroll 8
            for (int i = 0; i < in; i++) acc += xs[nl][i] * root[i * 64 + o];
            pre[(size_t)n * 64 + o] = acc;
            atomicAdd(&lsum[o], acc);
            atomicAdd(&lsq[o], acc * acc);
        }
    }
    __syncthreads();
    if (threadIdx.x < 64) {
        atomicAdd(&stats[threadIdx.x], lsum[threadIdx.x]);
        atomicAdd(&stats[64 + threadIdx.x], lsq[threadIdx.x]);
    }
}

// ---------------------------------------------------------------------------
// BN (batch stats, biased var) + ReLU. mode 0: store xn. mode 1: segment-max pool.
__global__ __launch_bounds__(256) void bn_apply(const float* __restrict__ pre,
                                                const float* __restrict__ stats,
                                                const float* __restrict__ gamma,
                                                const float* __restrict__ beta,
                                                float* __restrict__ xn,
                                                const int* __restrict__ batch,
                                                float* __restrict__ pooled,
                                                int mode) {
    int idx = blockIdx.x * 256 + threadIdx.x;
    if (idx >= N_NODES * 64) return;
    const int o = idx & 63, n = idx >> 6;
    const float inv = 1.f / (float)N_NODES;
    float mu = stats[o] * inv;
    float var = stats[64 + o] * inv - mu * mu;
    float sc = gamma[o] * rsqrtf(var + EPS);
    float sh = beta[o] - mu * sc;
    float v = fmaxf(pre[idx] * sc + sh, 0.f);
    if (mode == 0) xn[idx] = v;
    else atomicMax((int*)&pooled[(size_t)batch[n] * 64 + o], __float_as_int(v));
}

// ---------------------------------------------------------------------------
// out[g] = pp_b2 + relu(cat(pooled[g],u[g]) @ pp_w1 + pp_b1) @ pp_w2
__global__ __launch_bounds__(64) void final_mlp(const float* __restrict__ pooled,
                                                const float* __restrict__ u,
                                                const float* __restrict__ w1,
                                                const float* __restrict__ b1,
                                                const float* __restrict__ w2,
                                                const float* __restrict__ b2,
                                                float* __restrict__ out) {
    const int g = blockIdx.x, t = threadIdx.x;
    float acc = b1[t];
#pragma unroll 8
    for (int i = 0; i < 64; i++) acc += pooled[g * 64 + i] * w1[i * 64 + t];
#pragma unroll
    for (int j = 0; j < GIN; j++) acc += u[g * GIN + j] * w1[(64 + j) * 64 + t];
    float hv = fmaxf(acc, 0.f) * w2[t];
#pragma unroll
    for (int off = 32; off > 0; off >>= 1) hv += __shfl_down(hv, off, 64);
    if (t == 0) out[g] = hv + b2[0];
}

// ---------------------------------------------------------------------------
extern "C" void kernel_launch(void* const* d_in, const int* in_sizes, int n_in,
                              void* d_out, int out_size, void* d_ws, size_t ws_size,
                              hipStream_t stream) {
    const float* x0      = (const float*)d_in[0];
    const int*   ei      = (const int*)d_in[1];
    const int*   src     = ei;
    const int*   dst     = ei + N_EDGES;
    const float* ea      = (const float*)d_in[2];
    const int*   batch   = (const int*)d_in[3];
    const float* u       = (const float*)d_in[4];
    const float* e0w1    = (const float*)d_in[5];
    const float* e0b1    = (const float*)d_in[6];
    const float* e0w2    = (const float*)d_in[7];
    const float* e0b2    = (const float*)d_in[8];
    const float* root0   = (const float*)d_in[9];
    const float* bias0   = (const float*)d_in[10];
    const float* gamma0  = (const float*)d_in[11];
    const float* beta0   = (const float*)d_in[12];
    const float* ew1     = (const float*)d_in[13];
    const float* eb1     = (const float*)d_in[14];
    const float* ew2     = (const float*)d_in[15];
    const float* eb2     = (const float*)d_in[16];
    const float* rootl   = (const float*)d_in[17];
    const float* biasl   = (const float*)d_in[18];
    const float* gammal  = (const float*)d_in[19];
    const float* betal   = (const float*)d_in[20];
    const float* pp_w1   = (const float*)d_in[21];
    const float* pp_b1   = (const float*)d_in[22];
    const float* pp_w2   = (const float*)d_in[23];
    const float* pp_b2   = (const float*)d_in[24];

    float* ws = (float*)d_ws;
    size_t off = 0;
    f16*   ht     = (f16*)(ws + off); off += (size_t)N_EDGES * KDIM / 2;  // 3.2M fl
    f16*   xf     = (f16*)(ws + off); off += (size_t)N_NODES * 64 / 2;
    f16*   Bg     = (f16*)(ws + off); off += (size_t)129 * 4096 / 2;
    float* agg    = ws + off; off += (size_t)N_NODES * 64;
    float* xa     = ws + off; off += (size_t)N_NODES * 64;
    float* xb     = ws + off; off += (size_t)N_NODES * 64;
    float* stats  = ws + off; off += 256;
    float* pooled = ws + off; off += (size_t)NG * 64;

    hipMemsetAsync(pooled, 0, (size_t)NG * 64 * 4, stream);

    struct Layer {
        const float *w1, *b1, *w2, *b2, *root, *bias, *gamma, *beta, *xin;
        float* xout; int in, inshift, mode;
    };
    Layer L[4];
    L[0] = {e0w1, e0b1, e0w2, e0b2, root0, bias0, gamma0, beta0, x0, xa, IN0, 5, 0};
    for (int l = 0; l < 3; l++) {
        const float* xin  = (l == 0) ? xa : ((l == 1) ? xb : xa);
        float*       xout = (l == 0) ? xb : ((l == 1) ? xa : nullptr);
        L[l + 1] = {ew1 + (size_t)l * EDGE_IN * KDIM, eb1 + (size_t)l * KDIM,
                    ew2 + (size_t)l * KDIM * (HID * HID), eb2 + (size_t)l * (HID * HID),
                    rootl + (size_t)l * HID * HID, biasl + (size_t)l * HID,
                    gammal + (size_t)l * HID, betal + (size_t)l * HID,
                    xin, xout, HID, 6, (l == 2) ? 1 : 0};
    }

    const int eblocks = (N_EDGES + 255) / 256;               // 196
    const int ablocks = (N_NODES * 64 + 255) / 256;

    for (int l = 0; l < 4; l++) {
        const Layer& P = L[l];
        // nch: ceil((in*128 + in) / 64) == 2*in + 1
        const int nch = (P.in * 129 + 63) / 64;
        ht_kernel<<<eblocks, 256, 0, stream>>>(ea, P.w1, P.b1, ht);
        xconv<<<(N_NODES * P.in + 255) / 256, 256, 0, stream>>>(P.xin, xf, N_NODES * P.in);
        bconv<<<nch, 256, 0, stream>>>(P.w2, P.b2, Bg, P.in, P.inshift);
        hipMemsetAsync(agg, 0, (size_t)N_NODES * 64 * 4, stream);
        hipMemsetAsync(stats, 0, 128 * 4, stream);
        fused_msg<<<dim3(eblocks, KSEG), 256, 0, stream>>>(ht, xf, Bg, src, dst, agg,
                                                           P.in, P.inshift, nch);
        pre_stats<<<512, 256, 0, stream>>>(agg, P.xin, P.root, P.bias, agg, stats,
                                           P.in, P.inshift);
        bn_apply<<<ablocks, 256, 0, stream>>>(agg, stats, P.gamma, P.beta, P.xout,
                                              batch, pooled, P.mode);
    }
    final_mlp<<<NG, 64, 0, stream>>>(pooled, u, pp_w1, pp_b1, pp_w2, pp_b2,
                                     (float*)d_out);
}